// Round 9
// baseline (215.481 us; speedup 1.0000x reference)
//
#include <hip/hip_runtime.h>

// Problem constants
#define B_DIM 32
#define V_DIM 21
#define D_DIM 512
#define P_DIM 64
#define M_TOTAL 672          // B*V
#define K_TOTAL 32768        // D*P
#define OUT_DIM 96
#define E_DIM 8
#define R_DIM 8
#define H_DIM 256
#define N_TOTAL 160          // OUT_DIM + E*R
#define SCALING 2.0f
#define POOL_SCALE (1.0f / (V_DIM * (float)P_DIM))

// GEMM tiling (all-bf16; coalesced LDS staging; no conversion in loop)
#define BM 64
#define BK 64
#define KSPLIT 64
#define K_PER_SPLIT (K_TOTAL / KSPLIT)   // 512
#define CHUNKS (K_PER_SPLIT / BK)        // 8
#define LDS_K (BK + 8)                   // 72 shorts/row (144 B): frag reads 2-way alias
#define SMN (M_TOTAL * N_TOTAL)          // 107520 per partial plane
#define RC_ROWS 2                        // rows per reduce_combine block

// conv kernel split
#define XCONV_BLOCKS 10752               // 672*32768/8/256
#define WCONV_BLOCKS 2560                // 160*32768/8/256

typedef __attribute__((ext_vector_type(4))) float floatx4;
typedef __attribute__((ext_vector_type(8))) short short8;

__device__ __forceinline__ unsigned short f2bf(float f) {
  union { float f; unsigned int u; } v; v.f = f;
  unsigned int u = v.u + (0x7FFFu + ((v.u >> 16) & 1u));  // RNE
  return (unsigned short)(u >> 16);
}

// ------- conv: x fp32 -> xb bf16 (+fused pooling) AND [W_base|lora_A] -> Wb --
__global__ __launch_bounds__(256)
void conv_kernel(const float* __restrict__ x, const float* __restrict__ W_base,
                 const float* __restrict__ lora_A, short* __restrict__ xb,
                 short* __restrict__ Wb, float* __restrict__ pooled) {
  const int tid = threadIdx.x;
  if (blockIdx.x < XCONV_BLOCKS) {
    // x convert + pool. Each thread: 8 consecutive k of one row m (one d).
    size_t gid = (size_t)blockIdx.x * 256 + tid;
    const int m = (int)(gid >> 12);           // 4096 groups of 8 per row
    const int grp = (int)(gid & 4095);
    const float* src = x + ((size_t)m << 15) + grp * 8;
    floatx4 v0 = ((const floatx4*)src)[0];
    floatx4 v1 = ((const floatx4*)src)[1];
    short8 sv;
    sv[0] = (short)f2bf(v0[0]); sv[1] = (short)f2bf(v0[1]);
    sv[2] = (short)f2bf(v0[2]); sv[3] = (short)f2bf(v0[3]);
    sv[4] = (short)f2bf(v1[0]); sv[5] = (short)f2bf(v1[1]);
    sv[6] = (short)f2bf(v1[2]); sv[7] = (short)f2bf(v1[3]);
    *(short8*)(xb + gid * 8) = sv;
    // pooling: 8 lanes (same d = grp>>3) reduce, 1 atomic per group
    float s = ((v0[0] + v0[1]) + (v0[2] + v0[3])) +
              ((v1[0] + v1[1]) + (v1[2] + v1[3]));
    s += __shfl_down(s, 4, 8);
    s += __shfl_down(s, 2, 8);
    s += __shfl_down(s, 1, 8);
    if ((tid & 7) == 0) {
      int b = m / V_DIM;
      int d = grp >> 3;
      atomicAdd(&pooled[b * D_DIM + d], s * POOL_SCALE);
    }
  } else {
    // W convert (row-major Wb), coalesced read+write
    size_t base = ((size_t)(blockIdx.x - XCONV_BLOCKS) * 256 + tid) * 8;
    int row = (int)(base >> 15);
    int k = (int)(base & 32767);
    const float* src = (row < OUT_DIM) ? (W_base + ((size_t)row << 15) + k)
                                       : (lora_A + ((size_t)(row - OUT_DIM) << 15) + k);
    floatx4 v0 = ((const floatx4*)src)[0];
    floatx4 v1 = ((const floatx4*)src)[1];
    short8 sv;
    sv[0] = (short)f2bf(v0[0]); sv[1] = (short)f2bf(v0[1]);
    sv[2] = (short)f2bf(v0[2]); sv[3] = (short)f2bf(v0[3]);
    sv[4] = (short)f2bf(v1[0]); sv[5] = (short)f2bf(v1[1]);
    sv[6] = (short)f2bf(v1[2]); sv[7] = (short)f2bf(v1[3]);
    *(short8*)(Wb + base) = sv;
  }
}

// ------- gemm: P[ky][m][n] = xb-chunk @ Wb^T; pure bf16, LDS-staged, no VALU
__global__ __launch_bounds__(256, 4)
void gemm_kernel(const short* __restrict__ xb, const short* __restrict__ Wb,
                 float* __restrict__ P) {
  __shared__ short ldsA[BM * LDS_K];      //  9,216 B
  __shared__ short ldsB[N_TOTAL * LDS_K]; // 23,040 B
  const int tid = threadIdx.x;
  const int m0 = blockIdx.x * BM;
  const int ky = blockIdx.y;
  const int kbase = ky * K_PER_SPLIT;
  const int lane = tid & 63;
  const int wave = tid >> 6;
  const int quad = lane >> 4;
  const int l16 = lane & 15;

  floatx4 acc[10];                        // wave: rows [wave*16,+16), all 160 n
  #pragma unroll
  for (int nt = 0; nt < 10; ++nt) acc[nt] = (floatx4)(0.0f);

  // staging: A: idx=it*256+tid -> arow=idx>>3 (8 lanes/row, 128B contiguous),
  // g=idx&7 (short8 units). B: same pattern over 160 rows (5 iters).
  short8 pa[2];
  short8 pb[5];

#define ISSUE(c)                                                                \
  {                                                                             \
    const int kc = kbase + (c) * BK;                                            \
    _Pragma("unroll")                                                           \
    for (int it = 0; it < 2; ++it) {                                            \
      int idx = it * 256 + tid;                                                 \
      int arow = idx >> 3;                                                      \
      int g = idx & 7;                                                          \
      int m = m0 + arow;                                                        \
      pa[it] = (m < M_TOTAL)                                                    \
          ? *(const short8*)(xb + ((size_t)m << 15) + kc + g * 8)               \
          : (short8)(0);                                                        \
    }                                                                           \
    _Pragma("unroll")                                                           \
    for (int it = 0; it < 5; ++it) {                                            \
      int idx = it * 256 + tid;                                                 \
      int brow = idx >> 3;                                                      \
      int g = idx & 7;                                                          \
      pb[it] = *(const short8*)(Wb + ((size_t)brow << 15) + kc + g * 8);        \
    }                                                                           \
  }

#define WRITE_LDS()                                                             \
  {                                                                             \
    _Pragma("unroll")                                                           \
    for (int it = 0; it < 2; ++it) {                                            \
      int idx = it * 256 + tid;                                                 \
      int arow = idx >> 3;                                                      \
      int g = idx & 7;                                                          \
      *(short8*)&ldsA[arow * LDS_K + g * 8] = pa[it];                           \
    }                                                                           \
    _Pragma("unroll")                                                           \
    for (int it = 0; it < 5; ++it) {                                            \
      int idx = it * 256 + tid;                                                 \
      int brow = idx >> 3;                                                      \
      int g = idx & 7;                                                          \
      *(short8*)&ldsB[brow * LDS_K + g * 8] = pb[it];                           \
    }                                                                           \
  }

  ISSUE(0);
  WRITE_LDS();

  for (int c = 0; c < CHUNKS; ++c) {
    __syncthreads();        // LDS tiles for chunk c ready
    if (c + 1 < CHUNKS) ISSUE(c + 1);     // next chunk's loads fly under MFMA
    #pragma unroll
    for (int ks = 0; ks < 2; ++ks) {
      const int ko = ks * 32 + quad * 8;
      short8 a = *(const short8*)&ldsA[(wave * 16 + l16) * LDS_K + ko];
      #pragma unroll
      for (int nt = 0; nt < 10; ++nt) {
        short8 b = *(const short8*)&ldsB[(nt * 16 + l16) * LDS_K + ko];
        acc[nt] = __builtin_amdgcn_mfma_f32_16x16x32_bf16(a, b, acc[nt], 0, 0, 0);
      }
    }
    __syncthreads();        // all LDS reads of chunk c done
    if (c + 1 < CHUNKS) WRITE_LDS();
  }

  // partial-plane store (D layout: col=lane&15, row=quad*4+reg) — plain stores
  {
    const int mrow = m0 + wave * 16 + quad * 4;
    float* Pp = P + (size_t)ky * SMN + (size_t)mrow * N_TOTAL + l16;
    #pragma unroll
    for (int r = 0; r < 4; ++r)
      if (mrow + r < M_TOTAL)
        #pragma unroll
        for (int nt = 0; nt < 10; ++nt)
          Pp[(size_t)r * N_TOTAL + nt * 16] = acc[nt][r];
  }
}

// ---------------- router: MLP + softmax + top-2 ------------------------------
__global__ __launch_bounds__(256)
void router_kernel(const float* __restrict__ pooled, const float* __restrict__ W1,
                   const float* __restrict__ b1, const float* __restrict__ W2,
                   const float* __restrict__ b2, float* __restrict__ wfull,
                   float* __restrict__ probs_out) {
  __shared__ float sp[D_DIM];
  __shared__ float sh[H_DIM];
  __shared__ float slog[E_DIM];
  const int b = blockIdx.x;
  const int t = threadIdx.x;
  sp[t] = pooled[b * D_DIM + t];
  sp[t + 256] = pooled[b * D_DIM + t + 256];
  __syncthreads();
  float acc = b1[t];
  const float* w1r = W1 + (size_t)t * D_DIM;
  for (int d = 0; d < D_DIM; ++d) acc += sp[d] * w1r[d];
  sh[t] = fmaxf(acc, 0.0f);
  __syncthreads();
  if (t < E_DIM) {
    float a = b2[t];
    const float* w2r = W2 + t * H_DIM;
    for (int j = 0; j < H_DIM; ++j) a += sh[j] * w2r[j];
    slog[t] = a;
  }
  __syncthreads();
  if (t == 0) {
    float p[E_DIM];
    float mx = slog[0];
    for (int e = 1; e < E_DIM; ++e) mx = fmaxf(mx, slog[e]);
    float se = 0.0f;
    for (int e = 0; e < E_DIM; ++e) { p[e] = __expf(slog[e] - mx); se += p[e]; }
    float inv = 1.0f / se;
    for (int e = 0; e < E_DIM; ++e) { p[e] *= inv; probs_out[b * E_DIM + e] = p[e]; }
    // top-2, lowest index wins ties (strict > keeps earlier index)
    int i0 = 0;
    for (int e = 1; e < E_DIM; ++e) if (p[e] > p[i0]) i0 = e;
    int i1 = (i0 == 0) ? 1 : 0;
    for (int e = 0; e < E_DIM; ++e) if (e != i0 && p[e] > p[i1]) i1 = e;
    float s2 = p[i0] + p[i1];
    float invs = 1.0f / fmaxf(s2, 1e-6f);
    for (int e = 0; e < E_DIM; ++e) {
      float w = 0.0f;
      if (e == i0) w += p[i0] * invs;
      if (e == i1) w += p[i1] * invs;
      wfull[b * E_DIM + e] = w;
    }
  }
}

// ------- reduce partials over KSPLIT + combine: out = S_b + b_base + 2*Σ w·(S_l·B)
__global__ __launch_bounds__(256)
void reduce_combine_kernel(const float* __restrict__ P, const float* __restrict__ b_base,
                           const float* __restrict__ lora_B, const float* __restrict__ wfull,
                           float* __restrict__ out) {
  __shared__ float sS[RC_ROWS * N_TOTAL];   // 320 floats
  const int t = threadIdx.x;
  const size_t base = (size_t)blockIdx.x * (RC_ROWS * N_TOTAL);
  for (int s = t; s < RC_ROWS * N_TOTAL; s += 256) {
    const float* Pp = P + base + s;
    float a = 0.0f;
    #pragma unroll 8
    for (int k = 0; k < KSPLIT; ++k) a += Pp[(size_t)k * SMN];
    sS[s] = a;
  }
  __syncthreads();
  if (t < RC_ROWS * OUT_DIM) {
    int mr = t / OUT_DIM;
    int o = t - mr * OUT_DIM;
    int mm = blockIdx.x * RC_ROWS + mr;
    int b = mm / V_DIM;
    const float* srow = sS + mr * N_TOTAL;
    float res = srow[o] + b_base[o];
    float moe = 0.0f;
    #pragma unroll
    for (int e = 0; e < E_DIM; ++e) {
      float we = wfull[b * E_DIM + e];
      if (we != 0.0f) {
        const float* lb = lora_B + ((size_t)e * OUT_DIM + o) * R_DIM;
        float dd = 0.0f;
        #pragma unroll
        for (int r = 0; r < R_DIM; ++r) dd += srow[OUT_DIM + e * R_DIM + r] * lb[r];
        moe += we * dd;
      }
    }
    out[(size_t)mm * OUT_DIM + o] = res + SCALING * moe;
  }
}

extern "C" void kernel_launch(void* const* d_in, const int* in_sizes, int n_in,
                              void* d_out, int out_size, void* d_ws, size_t ws_size,
                              hipStream_t stream) {
  const float* x      = (const float*)d_in[0];
  const float* W_base = (const float*)d_in[1];
  const float* b_base = (const float*)d_in[2];
  const float* W1     = (const float*)d_in[3];
  const float* b1     = (const float*)d_in[4];
  const float* W2     = (const float*)d_in[5];
  const float* b2     = (const float*)d_in[6];
  const float* lora_A = (const float*)d_in[7];
  const float* lora_B = (const float*)d_in[8];
  float* out = (float*)d_out;

  // ws: pooled[16384 f] | wfull[256 f] | Wb[160*32768 s] | xb[672*32768 s] | P[64*107520 f]
  float* ws     = (float*)d_ws;
  float* pooled = ws;
  float* wfull  = ws + 16384;
  short* Wb     = (short*)(wfull + 256);
  short* xb     = Wb + (size_t)N_TOTAL * K_TOTAL;
  float* P      = (float*)(xb + (size_t)M_TOTAL * K_TOTAL);

  (void)hipMemsetAsync(pooled, 0, 16384 * sizeof(float), stream);
  conv_kernel<<<XCONV_BLOCKS + WCONV_BLOCKS, 256, 0, stream>>>(
      x, W_base, lora_A, xb, Wb, pooled);
  router_kernel<<<B_DIM, 256, 0, stream>>>(pooled, W1, b1, W2, b2, wfull,
                                           out + (size_t)M_TOTAL * OUT_DIM);
  gemm_kernel<<<dim3(11, KSPLIT), 256, 0, stream>>>(xb, Wb, P);
  reduce_combine_kernel<<<M_TOTAL / RC_ROWS, 256, 0, stream>>>(
      P, b_base, lora_B, wfull, out);
}